// Round 3
// baseline (235.900 us; speedup 1.0000x reference)
//
#include <hip/hip_runtime.h>
#include <math.h>

// edge = a*box5(x) + b*box3(x) + c*x   (fused K5+K3 depthwise conv, zero pad)
// out  = abs(maxpool5(edge))           (maxpool pads with -inf)
// One wave (64 lanes x float4) == one full 256-px row. Each wave slides down a
// 32-row strip keeping all vertical context in register rings. No LDS.

#define TY 32
#define STEPS (TY + 8)

typedef float vfloat4 __attribute__((ext_vector_type(4)));  // native vec for nontemporal builtin

__global__ __launch_bounds__(256, 2)
void edgepool_kernel(const float* __restrict__ xin, float* __restrict__ yout) {
    const int lane  = threadIdx.x & 63;
    const int wave  = threadIdx.x >> 6;
    const int blk   = blockIdx.x;                 // 0..1023
    const int plane = blk >> 1;                   // 0..511  (= b*64 + c)
    const int strip = ((blk & 1) << 2) | wave;    // 0..7    (4 adjacent strips/block -> halo L1 reuse)
    const int y0    = strip * TY;

    const float4* __restrict__ in4  = (const float4*)xin + (size_t)plane * 16384;
    vfloat4*      __restrict__ out4 = (vfloat4*)    yout + (size_t)plane * 16384;

    const float Wa = -0.01f, Wb = -0.19f, Wc = 2.2f;
    const float NINF = -INFINITY;

    float Cr[3][4];   // raw input rows (center-tap ring)
    float P5[5][4];   // horizontal 5-box sums ring
    float Q3[4][4];   // horizontal 3-box sums ring
    float M5[5][4];   // horizontal 5-max of edge ring
#pragma unroll
    for (int j = 0; j < 4; ++j) {
        Cr[0][j] = Cr[1][j] = Cr[2][j] = 0.f;
        Q3[0][j] = Q3[1][j] = Q3[2][j] = Q3[3][j] = 0.f;
        P5[0][j] = P5[1][j] = P5[2][j] = P5[3][j] = P5[4][j] = 0.f;
        M5[0][j] = M5[1][j] = M5[2][j] = M5[3][j] = M5[4][j] = NINF;
    }

#pragma unroll
    for (int t = 0; t < STEPS; ++t) {
        const int  r   = y0 - 4 + t;                 // input row being consumed
        const bool rin = (unsigned)r < 256u;
        const int  rc  = rin ? r : (r < 0 ? 0 : 255);
        const float4 vv = in4[rc * 64 + lane];       // unconditional load (hoistable)
        const float v0 = rin ? vv.x : 0.f;
        const float v1 = rin ? vv.y : 0.f;
        const float v2 = rin ? vv.z : 0.f;
        const float v3 = rin ? vv.w : 0.f;

        // horizontal halo from neighbor lanes (zero-pad image edges)
        float lm2 = __shfl(v2, lane - 1, 64);
        float lm1 = __shfl(v3, lane - 1, 64);
        float rp0 = __shfl(v0, lane + 1, 64);
        float rp1 = __shfl(v1, lane + 1, 64);
        lm2 = (lane == 0)  ? 0.f : lm2;
        lm1 = (lane == 0)  ? 0.f : lm1;
        rp0 = (lane == 63) ? 0.f : rp0;
        rp1 = (lane == 63) ? 0.f : rp1;

        // horizontal box sums for this row
        const float h3_0 = lm1 + v0 + v1;
        const float h3_1 = v0 + v1 + v2;
        const float h3_2 = v1 + v2 + v3;
        const float h3_3 = v2 + v3 + rp0;
        const float h5_0 = lm2 + lm1 + v0 + v1 + v2;
        const float h5_1 = lm1 + v0 + v1 + v2 + v3;
        const float h5_2 = v0 + v1 + v2 + v3 + rp0;
        const float h5_3 = v1 + v2 + v3 + rp0 + rp1;

        const int tc = t % 3, tp = t % 5, tq = t % 4;  // compile-time after unroll
        Cr[tc][0] = v0;   Cr[tc][1] = v1;   Cr[tc][2] = v2;   Cr[tc][3] = v3;
        P5[tp][0] = h5_0; P5[tp][1] = h5_1; P5[tp][2] = h5_2; P5[tp][3] = h5_3;
        Q3[tq][0] = h3_0; Q3[tq][1] = h3_1; Q3[tq][2] = h3_2; Q3[tq][3] = h3_3;

        // edge row er = r - 2 (needs h5 rows r-4..r, h3 rows r-3..r-1, x row r-2)
        const int  er  = r - 2;
        const bool ein = (unsigned)er < 256u;
        const int a1 = (t + 4) % 5, a2 = (t + 3) % 5, a3 = (t + 2) % 5, a4 = (t + 1) % 5;
        const int b1 = (t + 3) % 4, b2 = (t + 2) % 4, b3 = (t + 1) % 4;
        const int cc = (t + 1) % 3;
        float e[4];
#pragma unroll
        for (int j = 0; j < 4; ++j) {
            const float S5 = P5[tp][j] + P5[a1][j] + P5[a2][j] + P5[a3][j] + P5[a4][j];
            const float S3 = Q3[b1][j] + Q3[b2][j] + Q3[b3][j];
            const float ev = fmaf(Wc, Cr[cc][j], fmaf(Wb, S3, Wa * S5));
            e[j] = ein ? ev : NINF;   // rows outside image are -inf for the maxpool
        }

        // horizontal 5-max of edge row (-inf pad at image edges)
        float el2 = __shfl(e[2], lane - 1, 64);
        float el1 = __shfl(e[3], lane - 1, 64);
        float er0 = __shfl(e[0], lane + 1, 64);
        float er1 = __shfl(e[1], lane + 1, 64);
        el2 = (lane == 0)  ? NINF : el2;
        el1 = (lane == 0)  ? NINF : el1;
        er0 = (lane == 63) ? NINF : er0;
        er1 = (lane == 63) ? NINF : er1;

        M5[tp][0] = fmaxf(fmaxf(fmaxf(el2, el1), fmaxf(e[0], e[1])), e[2]);
        M5[tp][1] = fmaxf(fmaxf(fmaxf(el1, e[0]), fmaxf(e[1], e[2])), e[3]);
        M5[tp][2] = fmaxf(fmaxf(fmaxf(e[0], e[1]), fmaxf(e[2], e[3])), er0);
        M5[tp][3] = fmaxf(fmaxf(fmaxf(e[1], e[2]), fmaxf(e[3], er0)), er1);

        // output row o = r - 4 (vertical 5-max over M5 ring), valid from t>=8
        if (t >= 8) {   // compile-time predicate after unroll
            const int o = r - 4;
            vfloat4 ov;
            ov.x = fabsf(fmaxf(fmaxf(fmaxf(M5[0][0], M5[1][0]), fmaxf(M5[2][0], M5[3][0])), M5[4][0]));
            ov.y = fabsf(fmaxf(fmaxf(fmaxf(M5[0][1], M5[1][1]), fmaxf(M5[2][1], M5[3][1])), M5[4][1]));
            ov.z = fabsf(fmaxf(fmaxf(fmaxf(M5[0][2], M5[1][2]), fmaxf(M5[2][2], M5[3][2])), M5[4][2]));
            ov.w = fabsf(fmaxf(fmaxf(fmaxf(M5[0][3], M5[1][3]), fmaxf(M5[2][3], M5[3][3])), M5[4][3]));
            __builtin_nontemporal_store(ov, &out4[o * 64 + lane]);
        }
    }
}

extern "C" void kernel_launch(void* const* d_in, const int* in_sizes, int n_in,
                              void* d_out, int out_size, void* d_ws, size_t ws_size,
                              hipStream_t stream) {
    const float* x   = (const float*)d_in[0];
    float*       out = (float*)d_out;
    // 512 planes x 8 strips = 4096 wave-tasks; 4 waves/block -> 1024 blocks.
    hipLaunchKernelGGL(edgepool_kernel, dim3(1024), dim3(256), 0, stream, x, out);
}